// Round 4
// baseline (365.817 us; speedup 1.0000x reference)
//
#include <hip/hip_runtime.h>
#include <math.h>

// Problem constants
#define N_   8
#define C_   32
#define CO_  32
#define K_   4
#define D_   24
#define H_   64
#define W_   64
#define HW_  (H_*W_)          // 4096
#define DHW_ (D_*HW_)         // 98304
#define WPC_ 27               // taps per (co,c): 3*3*3
#define WPN_ (CO_*C_*WPC_)    // 27648 combined weights per sample
#define CWC_ (C_*WPC_)        // 864 weights per (co)

// padded transposed x: [n][dp=26][hp=66][wp=66][c=32] bf16 (halo = 0)
#define DP_ 26
#define HP_ 66
#define WP_ 66
#define ROW_ (WP_*C_)                           // 2112 ushorts = 4224 B per padded row
#define XT_PER_N ((size_t)DP_*HP_*WP_*C_)       // 3,624,192 elems
#define XT_BYTES (XT_PER_N * N_ * 2)            // 57,987,072 B
#define STATS_BYTES ((size_t)N_*C_*45*4)        // 46,080 B  (45 sums per (n,c))
#define ATT_BYTES   ((size_t)N_*K_*4)           // 128 B

typedef float f32x4  __attribute__((ext_vector_type(4)));
typedef short bf16x8 __attribute__((ext_vector_type(8)));
typedef unsigned int u32x4 __attribute__((ext_vector_type(4)));

__device__ inline unsigned short f2bf(float f) {
    unsigned u = __float_as_uint(f);
    unsigned r = (u + 0x7fffu + ((u >> 16) & 1u)) >> 16;
    return (unsigned short)r;
}

// async 16B global->LDS (width=16 => global_load_lds_dwordx4).
// LDS dest is wave-uniform base + lane*16 (pass a per-wave-uniform lds ptr).
__device__ __forceinline__ void gl16(const void* g, void* l) {
    __builtin_amdgcn_global_load_lds(
        (const __attribute__((address_space(1))) unsigned int*)g,
        (__attribute__((address_space(3))) unsigned int*)l, 16, 0, 0);
}

// ---------------------------------------------------------------------------
// Kernel A: zero the xt halo rows (dp=0, dp=25 planes; hp=0/65 rows) + stats.
// ---------------------------------------------------------------------------
__global__ __launch_bounds__(256) void k_zero(unsigned short* __restrict__ xt,
                                              float* __restrict__ stats) {
    int bid = blockIdx.x;
    int tid = threadIdx.x;
    u32x4 z = {0u, 0u, 0u, 0u};
    if (bid < N_ * 180) {
        int n = bid / 180, rr = bid % 180;
        int dp, hp;
        if (rr < 66)       { dp = 0;  hp = rr; }
        else if (rr < 132) { dp = 25; hp = rr - 66; }
        else { int r2 = rr - 132; dp = 1 + (r2 >> 1); hp = (r2 & 1) ? 65 : 0; }
        unsigned short* row = xt + ((size_t)(n * DP_ + dp) * HP_ + hp) * ROW_;
        *(u32x4*)(row + (size_t)tid * 8) = z;
        if (tid < 8) *(u32x4*)(row + (size_t)(256 + tid) * 8) = z;
    } else {
        int idx = (bid - N_ * 180) * 256 + tid;          // 16 B chunks of stats
        if (idx < (int)(STATS_BYTES / 16)) ((u32x4*)stats)[idx] = z;
    }
}

// ---------------------------------------------------------------------------
// Kernel B v2: fused pack + stats, latency-optimized.
// Grid = N*D*16 blocks (4 h-rows each). All 8 global loads issued up-front
// (128 B/thread in flight), 4 LDS row-tiles, ONE barrier, 4 coalesced 16 B
// stores/thread. Same transpose & stats math as the verified v1.
// ---------------------------------------------------------------------------
__global__ __launch_bounds__(256, 6) void k_packstats(const float* __restrict__ X,
                                                      unsigned short* __restrict__ xt,
                                                      float* __restrict__ stats) {
    int bid = blockIdx.x;
    int hq = bid & 15;                   // 16 h-quarters of 4 rows
    int d  = (bid >> 4) % D_;
    int n  = bid / (16 * D_);
    int tid = threadIdx.x;
    int h0 = hq << 2;

    __shared__ unsigned short T[4][64][34];   // 17,408 B

    // load role: thread owns channel c, 8 consecutive w, 4 rows
    int c  = tid >> 3;
    int w8 = (tid & 7) << 3;
    const float* xr = X + (size_t)(n * C_ + c) * DHW_ + (size_t)d * HW_ + w8;

    f32x4 a[4], b[4];
#pragma unroll
    for (int rr = 0; rr < 4; rr++) {
        a[rr] = *(const f32x4*)(xr + (size_t)(h0 + rr) * W_);
        b[rr] = *(const f32x4*)(xr + (size_t)(h0 + rr) * W_ + 4);
    }

    float ps[9];
#pragma unroll
    for (int j = 0; j < 9; j++) ps[j] = 0.f;
    bool w0lane  = (tid & 7) == 0;
    bool w63lane = (tid & 7) == 7;

#pragma unroll
    for (int rr = 0; rr < 4; rr++) {
        int h = h0 + rr;
        float s8 = a[rr][0] + a[rr][1] + a[rr][2] + a[rr][3]
                 + b[rr][0] + b[rr][1] + b[rr][2] + b[rr][3];
        ps[0] += s8;
        if (w0lane)  ps[3] += a[rr][0];
        if (w63lane) ps[4] += b[rr][3];
        if (h == 0)  { ps[1] += s8; if (w0lane) ps[5] += a[rr][0]; if (w63lane) ps[6] += b[rr][3]; }
        if (h == 63) { ps[2] += s8; if (w0lane) ps[7] += a[rr][0]; if (w63lane) ps[8] += b[rr][3]; }

#pragma unroll
        for (int j = 0; j < 4; j++) {
            T[rr][w8 + j][c]     = f2bf(a[rr][j]);
            T[rr][w8 + 4 + j][c] = f2bf(b[rr][j]);
        }
    }
    __syncthreads();

    // store role: thread owns (wp, 8 consecutive c), 4 rows
    int wp = tid >> 2;               // 0..63
    int c0 = (tid & 3) << 3;
    unsigned short* oplane = xt + ((size_t)(n * DP_ + d + 1) * HP_) * ROW_;
#pragma unroll
    for (int rr = 0; rr < 4; rr++) {
        unsigned short* orow = oplane + (size_t)(h0 + rr + 1) * ROW_;
        const unsigned int* src = (const unsigned int*)&T[rr][wp][c0]; // 4B-aligned
        u32x4 o = { src[0], src[1], src[2], src[3] };
        *(u32x4*)(orow + (size_t)(wp + 1) * C_ + c0) = o;
        // w halo (wp=0 and wp=65) is always zero
        if (tid < 4)      *(u32x4*)(orow + (size_t)tid * 8) = (u32x4){0u,0u,0u,0u};
        else if (tid < 8) *(u32x4*)(orow + (size_t)65 * C_ + (tid - 4) * 8) = (u32x4){0u,0u,0u,0u};
    }

    // reduce the 8 threads sharing c, then atomically commit
#pragma unroll
    for (int j = 0; j < 9; j++) {
        float v = ps[j];
        v += __shfl_down(v, 4);
        v += __shfl_down(v, 2);
        v += __shfl_down(v, 1);
        ps[j] = v;
    }
    if ((tid & 7) == 0) {
        float* sb = stats + (size_t)(n * C_ + c) * 45;
#pragma unroll
        for (int j = 0; j < 9; j++) atomicAdd(&sb[j], ps[j]);
        int cat = (d == 0) ? 1 : (d == 1) ? 2 : (d == 22) ? 3 : (d == 23) ? 4 : 0;
        if (cat) {
#pragma unroll
            for (int j = 0; j < 9; j++) atomicAdd(&sb[cat * 9 + j], ps[j]);
        }
    }
}

// ---------------------------------------------------------------------------
// Kernel C: attention logits + softmax (unchanged — verified round 1).
// ---------------------------------------------------------------------------
__global__ __launch_bounds__(128) void k_att(const float* __restrict__ stats,
                                             const float* __restrict__ aw1,
                                             const float* __restrict__ ab1,
                                             const float* __restrict__ aw2,
                                             const float* __restrict__ ab2,
                                             const float* __restrict__ aw3,
                                             const float* __restrict__ ab3,
                                             float* __restrict__ attG) {
    int n = blockIdx.x;
    int tid = threadIdx.x;
    __shared__ float xaL[K_];

    int k = tid >> 5;
    int c = tid & 31;
    const float* st = stats + (size_t)(n * C_ + c) * 45;
    float s45[45];
#pragma unroll
    for (int j = 0; j < 45; j++) s45[j] = st[j];

    float Qs[5][9];
#pragma unroll
    for (int set = 0; set < 5; set++) {
        const float* S = s45 + set * 9;
#pragma unroll
        for (int oh = -1; oh <= 1; oh++) {
#pragma unroll
            for (int ow = -1; ow <= 1; ow++) {
                float q = S[0];
                if (oh == 1)  q -= S[1];
                if (oh == -1) q -= S[2];
                if (ow == 1)  q -= S[3];
                if (ow == -1) q -= S[4];
                if (oh == 1  && ow == 1)  q += S[5];
                if (oh == 1  && ow == -1) q += S[6];
                if (oh == -1 && ow == 1)  q += S[7];
                if (oh == -1 && ow == -1) q += S[8];
                Qs[set][(oh + 1) * 3 + (ow + 1)] = q;
            }
        }
    }
    auto box = [&](int od, int qi) {
        float b = Qs[0][qi];
        if (od == -2) b -= Qs[3][qi] + Qs[4][qi];
        if (od == -1) b -= Qs[4][qi];
        if (od ==  1) b -= Qs[1][qi];
        if (od ==  2) b -= Qs[1][qi] + Qs[2][qi];
        return b;
    };

    float sum = aw1[k * C_ + c] * Qs[0][4];
    const float* a2 = aw2 + (k * C_ + c) * 27;
    const float* a3 = aw3 + (k * C_ + c) * 45;
#pragma unroll
    for (int kd = 0; kd < 3; kd++)
#pragma unroll
        for (int kh = 0; kh < 3; kh++)
#pragma unroll
            for (int kw = 0; kw < 3; kw++)
                sum += a2[kd * 9 + kh * 3 + kw] * box(kd - 1, kh * 3 + kw);
#pragma unroll
    for (int kd = 0; kd < 5; kd++)
#pragma unroll
        for (int kh = 0; kh < 3; kh++)
#pragma unroll
            for (int kw = 0; kw < 3; kw++)
                sum += a3[kd * 9 + kh * 3 + kw] * box(kd - 2, kh * 3 + kw);

#pragma unroll
    for (int off = 16; off > 0; off >>= 1) sum += __shfl_down(sum, off, 32);
    if ((tid & 31) == 0) xaL[k] = sum;
    __syncthreads();
    if (tid == 0) {
        float xa[K_], mx = -1e30f;
#pragma unroll
        for (int kk = 0; kk < K_; kk++) {
            xa[kk] = xaL[kk] * (1.f / (float)DHW_) + ab1[kk] + ab2[kk] + ab3[kk];
            mx = fmaxf(mx, xa[kk]);
        }
        float ssum = 0.f, e[K_];
#pragma unroll
        for (int kk = 0; kk < K_; kk++) { e[kk] = expf(xa[kk] - mx); ssum += e[kk]; }
#pragma unroll
        for (int kk = 0; kk < K_; kk++) attG[n * K_ + kk] = e[kk] / ssum;
    }
}

// ---------------------------------------------------------------------------
// Kernel D: combined weights -> bf16 wn[n][t][co][c] (unchanged — verified).
// ---------------------------------------------------------------------------
__global__ __launch_bounds__(256) void k_wcomb(const float* __restrict__ attG,
                                               const float* __restrict__ weight,
                                               const float* __restrict__ conv_w,
                                               unsigned short* __restrict__ wn) {
    int bid = blockIdx.x;
    int co = bid & 31;
    int n  = bid >> 5;
    int tid = threadIdx.x;
    __shared__ unsigned short B[CWC_];

    float at0 = attG[n * K_ + 0], at1 = attG[n * K_ + 1];
    float at2 = attG[n * K_ + 2], at3 = attG[n * K_ + 3];
    const float* cw = conv_w + (size_t)co * CWC_;
    const float* wk = weight + (size_t)co * CWC_;
    for (int i = tid; i < CWC_; i += 256) {
        float v = cw[i] + at0 * wk[i] + at1 * wk[WPN_ + i]
                + at2 * wk[2 * WPN_ + i] + at3 * wk[3 * WPN_ + i];
        B[i] = f2bf(v);
    }
    __syncthreads();
    if (tid < 108) {
        int t  = tid >> 2;
        int c8 = (tid & 3) << 3;
        bf16x8 o;
#pragma unroll
        for (int j = 0; j < 8; j++) o[j] = (short)B[(c8 + j) * WPC_ + t];
        *(bf16x8*)(wn + (size_t)n * WPN_ + (size_t)t * (CO_ * C_) + co * C_ + c8) = o;
    }
}

// ---------------------------------------------------------------------------
// Kernel 3 v2: implicit-GEMM conv, LDS-staged (unchanged — verified round 3).
// ---------------------------------------------------------------------------
#define XCH_ 2640   // 42240 B / 16
#define WCH_ 1152   // 18432 B / 16
__global__ __launch_bounds__(256) void k_conv(const unsigned short* __restrict__ xt,
                                              const unsigned short* __restrict__ wn,
                                              const float* __restrict__ bias,
                                              float* __restrict__ out) {
    __shared__ __align__(16) unsigned short XB[10 * WP_ * C_];   // 21120
    __shared__ __align__(16) unsigned short WA[9 * CO_ * C_];    //  9216

    int blk = blockIdx.x;                 // n*D_*8 + d*8 + hb
    int hb = blk & 7;
    int t2 = blk >> 3;
    int d  = t2 % D_;
    int n  = t2 / D_;
    int h0 = hb << 3;

    int tid = threadIdx.x;
    int l   = tid & 63;
    int wid = tid >> 6;
    int nl  = l & 15;                     // spatial-in-tile (B n-dim, A m-dim)
    int kcg = l >> 4;                     // k-group (c/8)
    int kb  = kcg * 16;                   // byte offset of the 16B k-slice

    int bbase[2][4];
#pragma unroll
    for (int r = 0; r < 2; r++)
#pragma unroll
        for (int wq = 0; wq < 4; wq++)
            bbase[r][wq] = (((wid * 2 + r) * WP_) + wq * 16 + nl) * 64 + kb;
    int abase = nl * 64 + kb;             // + tl*2048 per tap; +1024 for A1

    f32x4 acc[2][4][2];
#pragma unroll
    for (int r = 0; r < 2; r++)
#pragma unroll
        for (int wq = 0; wq < 4; wq++)
#pragma unroll
            for (int hf = 0; hf < 2; hf++)
                acc[r][wq][hf] = (f32x4){0.f, 0.f, 0.f, 0.f};

    const unsigned short* xs0 = xt + ((size_t)(n * DP_ + d) * HP_ + h0) * ROW_;
    const unsigned short* ws0 = wn + (size_t)n * WPN_;
    int wun = tid & ~63;                  // wave-uniform lane-group base

#pragma unroll 1
    for (int od = 0; od < 3; od++) {
        const unsigned short* xs = xs0 + (size_t)od * ((size_t)HP_ * ROW_);
        const unsigned short* ws = ws0 + (size_t)od * 9 * (CO_ * C_);
#pragma unroll
        for (int base = 0; base < XCH_; base += 256) {
            int ch = base + tid;
            if (ch < XCH_)
                gl16(xs + (size_t)ch * 8, XB + (size_t)(base + wun) * 8);
        }
#pragma unroll
        for (int base = 0; base < WCH_; base += 256) {
            int ch = base + tid;
            if (ch < WCH_)
                gl16(ws + (size_t)ch * 8, WA + (size_t)(base + wun) * 8);
        }
        __syncthreads();                  // drains vmcnt before any ds_read

#pragma unroll
        for (int oh = 0; oh < 3; oh++) {
#pragma unroll
            for (int ow = 0; ow < 3; ow++) {
                int tl = oh * 3 + ow;
                const char* ab = (const char*)WA + tl * 2048 + abase;
                bf16x8 A0 = *(const bf16x8*)(ab);
                bf16x8 A1 = *(const bf16x8*)(ab + 1024);
#pragma unroll
                for (int r = 0; r < 2; r++)
#pragma unroll
                    for (int wq = 0; wq < 4; wq++) {
                        bf16x8 B = *(const bf16x8*)((const char*)XB
                                     + bbase[r][wq] + (oh * WP_ + ow) * 64);
                        acc[r][wq][0] = __builtin_amdgcn_mfma_f32_16x16x32_bf16(
                            A0, B, acc[r][wq][0], 0, 0, 0);
                        acc[r][wq][1] = __builtin_amdgcn_mfma_f32_16x16x32_bf16(
                            A1, B, acc[r][wq][1], 0, 0, 0);
                    }
            }
        }
        __syncthreads();                  // all reads done before next stage
    }

    int rquad = kcg << 2;
#pragma unroll
    for (int hf = 0; hf < 2; hf++)
#pragma unroll
        for (int j = 0; j < 4; j++) {
            int co = hf * 16 + rquad + j;
            float bv = bias[co];
#pragma unroll
            for (int r = 0; r < 2; r++) {
                int h = h0 + wid * 2 + r;
                float* op = out + ((size_t)(n * CO_ + co)) * DHW_
                                + (size_t)d * HW_ + (size_t)h * W_;
#pragma unroll
                for (int wq = 0; wq < 4; wq++)
                    op[wq * 16 + nl] = acc[r][wq][hf][j] + bv;
            }
        }
}

extern "C" void kernel_launch(void* const* d_in, const int* in_sizes, int n_in,
                              void* d_out, int out_size, void* d_ws, size_t ws_size,
                              hipStream_t stream) {
    const float* x      = (const float*)d_in[0];
    const float* weight = (const float*)d_in[1];
    const float* conv_w = (const float*)d_in[2];
    const float* conv_b = (const float*)d_in[3];
    const float* aw1    = (const float*)d_in[4];
    const float* ab1    = (const float*)d_in[5];
    const float* aw2    = (const float*)d_in[6];
    const float* ab2    = (const float*)d_in[7];
    const float* aw3    = (const float*)d_in[8];
    const float* ab3    = (const float*)d_in[9];
    float* out = (float*)d_out;

    unsigned short* xt  = (unsigned short*)d_ws;
    float* stats        = (float*)((char*)d_ws + XT_BYTES);
    float* attG         = (float*)((char*)d_ws + XT_BYTES + STATS_BYTES);
    unsigned short* wnb = (unsigned short*)((char*)d_ws + XT_BYTES + STATS_BYTES + ATT_BYTES);

    k_zero<<<dim3(N_ * 180 + 12), dim3(256), 0, stream>>>(xt, stats);
    k_packstats<<<dim3(N_ * D_ * 16), dim3(256), 0, stream>>>(x, xt, stats);
    k_att<<<dim3(N_), dim3(128), 0, stream>>>(stats, aw1, ab1, aw2, ab2, aw3, ab3, attG);
    k_wcomb<<<dim3(N_ * CO_), dim3(256), 0, stream>>>(attG, weight, conv_w, wnb);
    k_conv<<<dim3(N_ * D_ * 8), dim3(256), 0, stream>>>(xt, wnb, conv_b, out);
}

// Round 5
// 263.983 us; speedup vs baseline: 1.3858x; 1.3858x over previous
//
#include <hip/hip_runtime.h>
#include <math.h>

// Problem constants
#define N_   8
#define C_   32
#define CO_  32
#define K_   4
#define D_   24
#define H_   64
#define W_   64
#define HW_  (H_*W_)          // 4096
#define DHW_ (D_*HW_)         // 98304
#define WPC_ 27               // taps per (co,c): 3*3*3
#define WPN_ (CO_*C_*WPC_)    // 27648 combined weights per sample
#define CWC_ (C_*WPC_)        // 864 weights per (co)

// padded transposed x: [n][dp=26][hp=66][wp=66][c=32] bf16 (halo = 0)
#define DP_ 26
#define HP_ 66
#define WP_ 66
#define ROW_ (WP_*C_)                           // 2112 ushorts = 4224 B per padded row
#define XT_PER_N ((size_t)DP_*HP_*WP_*C_)       // 3,624,192 elems
#define XT_BYTES (XT_PER_N * N_ * 2)            // 57,987,072 B
#define STATS_BYTES ((size_t)N_*C_*45*4)        // 46,080 B  (45 sums per (n,c))
#define ATT_BYTES   ((size_t)N_*K_*4)           // 128 B
#define NPACK_ (N_*D_*16)                       // 3072 pack blocks
#define PART_BYTES ((size_t)NPACK_*288*4)       // 3,538,944 B (per-block 9x32 partials)

typedef float f32x4  __attribute__((ext_vector_type(4)));
typedef short bf16x8 __attribute__((ext_vector_type(8)));
typedef unsigned int u32x4 __attribute__((ext_vector_type(4)));

__device__ inline unsigned short f2bf(float f) {
    unsigned u = __float_as_uint(f);
    unsigned r = (u + 0x7fffu + ((u >> 16) & 1u)) >> 16;
    return (unsigned short)r;
}

// async 16B global->LDS (width=16 => global_load_lds_dwordx4).
// LDS dest is wave-uniform base + lane*16 (pass a per-wave-uniform lds ptr).
__device__ __forceinline__ void gl16(const void* g, void* l) {
    __builtin_amdgcn_global_load_lds(
        (const __attribute__((address_space(1))) unsigned int*)g,
        (__attribute__((address_space(3))) unsigned int*)l, 16, 0, 0);
}

// ---------------------------------------------------------------------------
// Kernel A: zero the xt halo rows (dp=0, dp=25 planes; hp=0/65 rows).
// (stats no longer needs zeroing: k_statreduce fully overwrites it)
// ---------------------------------------------------------------------------
__global__ __launch_bounds__(256) void k_zero(unsigned short* __restrict__ xt) {
    int bid = blockIdx.x;
    int tid = threadIdx.x;
    u32x4 z = {0u, 0u, 0u, 0u};
    int n = bid / 180, rr = bid % 180;
    int dp, hp;
    if (rr < 66)       { dp = 0;  hp = rr; }
    else if (rr < 132) { dp = 25; hp = rr - 66; }
    else { int r2 = rr - 132; dp = 1 + (r2 >> 1); hp = (r2 & 1) ? 65 : 0; }
    unsigned short* row = xt + ((size_t)(n * DP_ + dp) * HP_ + hp) * ROW_;
    *(u32x4*)(row + (size_t)tid * 8) = z;
    if (tid < 8) *(u32x4*)(row + (size_t)(256 + tid) * 8) = z;
}

// ---------------------------------------------------------------------------
// Kernel B v3: fused pack + stats partials. Grid = N*D*16 (4 h-rows each).
// v2 structure (loads up-front, one barrier, 4 coalesced stores) but the
// atomic commit is replaced by a per-block NON-ATOMIC partial record:
// part[bid][j=0..8][c=0..31], written as 1152 contiguous bytes (72x16B).
// ---------------------------------------------------------------------------
__global__ __launch_bounds__(256, 6) void k_packstats(const float* __restrict__ X,
                                                      unsigned short* __restrict__ xt,
                                                      float* __restrict__ part) {
    int bid = blockIdx.x;
    int hq = bid & 15;                   // 16 h-quarters of 4 rows
    int d  = (bid >> 4) % D_;
    int n  = bid / (16 * D_);
    int tid = threadIdx.x;
    int h0 = hq << 2;

    __shared__ unsigned short T[4][64][34];   // 17,408 B
    __shared__ float P[288];                  // 9 x 32 partial sums

    // load role: thread owns channel c, 8 consecutive w, 4 rows
    int c  = tid >> 3;
    int w8 = (tid & 7) << 3;
    const float* xr = X + (size_t)(n * C_ + c) * DHW_ + (size_t)d * HW_ + w8;

    f32x4 a[4], b[4];
#pragma unroll
    for (int rr = 0; rr < 4; rr++) {
        a[rr] = *(const f32x4*)(xr + (size_t)(h0 + rr) * W_);
        b[rr] = *(const f32x4*)(xr + (size_t)(h0 + rr) * W_ + 4);
    }

    float ps[9];
#pragma unroll
    for (int j = 0; j < 9; j++) ps[j] = 0.f;
    bool w0lane  = (tid & 7) == 0;
    bool w63lane = (tid & 7) == 7;

#pragma unroll
    for (int rr = 0; rr < 4; rr++) {
        int h = h0 + rr;
        float s8 = a[rr][0] + a[rr][1] + a[rr][2] + a[rr][3]
                 + b[rr][0] + b[rr][1] + b[rr][2] + b[rr][3];
        ps[0] += s8;
        if (w0lane)  ps[3] += a[rr][0];
        if (w63lane) ps[4] += b[rr][3];
        if (h == 0)  { ps[1] += s8; if (w0lane) ps[5] += a[rr][0]; if (w63lane) ps[6] += b[rr][3]; }
        if (h == 63) { ps[2] += s8; if (w0lane) ps[7] += a[rr][0]; if (w63lane) ps[8] += b[rr][3]; }

#pragma unroll
        for (int j = 0; j < 4; j++) {
            T[rr][w8 + j][c]     = f2bf(a[rr][j]);
            T[rr][w8 + 4 + j][c] = f2bf(b[rr][j]);
        }
    }

    // reduce the 8 threads sharing c while waiting for LDS visibility
#pragma unroll
    for (int j = 0; j < 9; j++) {
        float v = ps[j];
        v += __shfl_down(v, 4);
        v += __shfl_down(v, 2);
        v += __shfl_down(v, 1);
        ps[j] = v;
    }
    if ((tid & 7) == 0) {
#pragma unroll
        for (int j = 0; j < 9; j++) P[j * 32 + c] = ps[j];
    }
    __syncthreads();

    // store role: thread owns (wp, 8 consecutive c), 4 rows
    int wp = tid >> 2;               // 0..63
    int c0 = (tid & 3) << 3;
    unsigned short* oplane = xt + ((size_t)(n * DP_ + d + 1) * HP_) * ROW_;
#pragma unroll
    for (int rr = 0; rr < 4; rr++) {
        unsigned short* orow = oplane + (size_t)(h0 + rr + 1) * ROW_;
        const unsigned int* src = (const unsigned int*)&T[rr][wp][c0]; // 4B-aligned
        u32x4 o = { src[0], src[1], src[2], src[3] };
        *(u32x4*)(orow + (size_t)(wp + 1) * C_ + c0) = o;
        // w halo (wp=0 and wp=65) is always zero
        if (tid < 4)      *(u32x4*)(orow + (size_t)tid * 8) = (u32x4){0u,0u,0u,0u};
        else if (tid < 8) *(u32x4*)(orow + (size_t)65 * C_ + (tid - 4) * 8) = (u32x4){0u,0u,0u,0u};
    }

    // commit partials: 72 lanes x 16B, fully coalesced, non-atomic
    if (tid < 72)
        ((f32x4*)(part + (size_t)bid * 288))[tid] = ((const f32x4*)P)[tid];
}

// ---------------------------------------------------------------------------
// Kernel B2: reduce per-block partials -> stats[(n,c)][45].
// Grid = N*C = 256 blocks x 1 wave. Sums 384 records (d,hq) per (n,c),
// applying the d-category buckets (d==0/1/22/23) here.
// ---------------------------------------------------------------------------
__global__ __launch_bounds__(64) void k_statreduce(const float* __restrict__ part,
                                                   float* __restrict__ stats) {
    int b = blockIdx.x;              // n*32 + c
    int n = b >> 5, c = b & 31;
    int lane = threadIdx.x;          // 0..63

    float acc[45];
#pragma unroll
    for (int j = 0; j < 45; j++) acc[j] = 0.f;

#pragma unroll
    for (int it = 0; it < 6; it++) {
        int rid = it * 64 + lane;    // 0..383
        int d  = rid >> 4;
        int hq = rid & 15;
        const float* pr = part + (size_t)((n * D_ + d) * 16 + hq) * 288 + c;
        float v[9];
#pragma unroll
        for (int j = 0; j < 9; j++) v[j] = pr[j * 32];
#pragma unroll
        for (int j = 0; j < 9; j++) acc[j] += v[j];
        int cat = (d == 0) ? 1 : (d == 1) ? 2 : (d == 22) ? 3 : (d == 23) ? 4 : 0;
        if (cat) {
#pragma unroll
            for (int j = 0; j < 9; j++) acc[cat * 9 + j] += v[j];
        }
    }

#pragma unroll
    for (int j = 0; j < 45; j++) {
        float v = acc[j];
#pragma unroll
        for (int off = 32; off > 0; off >>= 1) v += __shfl_down(v, off);
        acc[j] = v;
    }
    if (lane == 0) {
        float* sb = stats + (size_t)b * 45;
#pragma unroll
        for (int j = 0; j < 45; j++) sb[j] = acc[j];
    }
}

// ---------------------------------------------------------------------------
// Kernel C: attention logits + softmax (unchanged — verified round 1).
// ---------------------------------------------------------------------------
__global__ __launch_bounds__(128) void k_att(const float* __restrict__ stats,
                                             const float* __restrict__ aw1,
                                             const float* __restrict__ ab1,
                                             const float* __restrict__ aw2,
                                             const float* __restrict__ ab2,
                                             const float* __restrict__ aw3,
                                             const float* __restrict__ ab3,
                                             float* __restrict__ attG) {
    int n = blockIdx.x;
    int tid = threadIdx.x;
    __shared__ float xaL[K_];

    int k = tid >> 5;
    int c = tid & 31;
    const float* st = stats + (size_t)(n * C_ + c) * 45;
    float s45[45];
#pragma unroll
    for (int j = 0; j < 45; j++) s45[j] = st[j];

    float Qs[5][9];
#pragma unroll
    for (int set = 0; set < 5; set++) {
        const float* S = s45 + set * 9;
#pragma unroll
        for (int oh = -1; oh <= 1; oh++) {
#pragma unroll
            for (int ow = -1; ow <= 1; ow++) {
                float q = S[0];
                if (oh == 1)  q -= S[1];
                if (oh == -1) q -= S[2];
                if (ow == 1)  q -= S[3];
                if (ow == -1) q -= S[4];
                if (oh == 1  && ow == 1)  q += S[5];
                if (oh == 1  && ow == -1) q += S[6];
                if (oh == -1 && ow == 1)  q += S[7];
                if (oh == -1 && ow == -1) q += S[8];
                Qs[set][(oh + 1) * 3 + (ow + 1)] = q;
            }
        }
    }
    auto box = [&](int od, int qi) {
        float b = Qs[0][qi];
        if (od == -2) b -= Qs[3][qi] + Qs[4][qi];
        if (od == -1) b -= Qs[4][qi];
        if (od ==  1) b -= Qs[1][qi];
        if (od ==  2) b -= Qs[1][qi] + Qs[2][qi];
        return b;
    };

    float sum = aw1[k * C_ + c] * Qs[0][4];
    const float* a2 = aw2 + (k * C_ + c) * 27;
    const float* a3 = aw3 + (k * C_ + c) * 45;
#pragma unroll
    for (int kd = 0; kd < 3; kd++)
#pragma unroll
        for (int kh = 0; kh < 3; kh++)
#pragma unroll
            for (int kw = 0; kw < 3; kw++)
                sum += a2[kd * 9 + kh * 3 + kw] * box(kd - 1, kh * 3 + kw);
#pragma unroll
    for (int kd = 0; kd < 5; kd++)
#pragma unroll
        for (int kh = 0; kh < 3; kh++)
#pragma unroll
            for (int kw = 0; kw < 3; kw++)
                sum += a3[kd * 9 + kh * 3 + kw] * box(kd - 2, kh * 3 + kw);

#pragma unroll
    for (int off = 16; off > 0; off >>= 1) sum += __shfl_down(sum, off, 32);
    if ((tid & 31) == 0) xaL[k] = sum;
    __syncthreads();
    if (tid == 0) {
        float xa[K_], mx = -1e30f;
#pragma unroll
        for (int kk = 0; kk < K_; kk++) {
            xa[kk] = xaL[kk] * (1.f / (float)DHW_) + ab1[kk] + ab2[kk] + ab3[kk];
            mx = fmaxf(mx, xa[kk]);
        }
        float ssum = 0.f, e[K_];
#pragma unroll
        for (int kk = 0; kk < K_; kk++) { e[kk] = expf(xa[kk] - mx); ssum += e[kk]; }
#pragma unroll
        for (int kk = 0; kk < K_; kk++) attG[n * K_ + kk] = e[kk] / ssum;
    }
}

// ---------------------------------------------------------------------------
// Kernel D: combined weights -> bf16 wn[n][t][co][c] (unchanged — verified).
// ---------------------------------------------------------------------------
__global__ __launch_bounds__(256) void k_wcomb(const float* __restrict__ attG,
                                               const float* __restrict__ weight,
                                               const float* __restrict__ conv_w,
                                               unsigned short* __restrict__ wn) {
    int bid = blockIdx.x;
    int co = bid & 31;
    int n  = bid >> 5;
    int tid = threadIdx.x;
    __shared__ unsigned short B[CWC_];

    float at0 = attG[n * K_ + 0], at1 = attG[n * K_ + 1];
    float at2 = attG[n * K_ + 2], at3 = attG[n * K_ + 3];
    const float* cw = conv_w + (size_t)co * CWC_;
    const float* wk = weight + (size_t)co * CWC_;
    for (int i = tid; i < CWC_; i += 256) {
        float v = cw[i] + at0 * wk[i] + at1 * wk[WPN_ + i]
                + at2 * wk[2 * WPN_ + i] + at3 * wk[3 * WPN_ + i];
        B[i] = f2bf(v);
    }
    __syncthreads();
    if (tid < 108) {
        int t  = tid >> 2;
        int c8 = (tid & 3) << 3;
        bf16x8 o;
#pragma unroll
        for (int j = 0; j < 8; j++) o[j] = (short)B[(c8 + j) * WPC_ + t];
        *(bf16x8*)(wn + (size_t)n * WPN_ + (size_t)t * (CO_ * C_) + co * C_ + c8) = o;
    }
}

// ---------------------------------------------------------------------------
// Kernel 3 v2: implicit-GEMM conv, LDS-staged (unchanged — verified round 3).
// ---------------------------------------------------------------------------
#define XCH_ 2640   // 42240 B / 16
#define WCH_ 1152   // 18432 B / 16
__global__ __launch_bounds__(256) void k_conv(const unsigned short* __restrict__ xt,
                                              const unsigned short* __restrict__ wn,
                                              const float* __restrict__ bias,
                                              float* __restrict__ out) {
    __shared__ __align__(16) unsigned short XB[10 * WP_ * C_];   // 21120
    __shared__ __align__(16) unsigned short WA[9 * CO_ * C_];    //  9216

    int blk = blockIdx.x;                 // n*D_*8 + d*8 + hb
    int hb = blk & 7;
    int t2 = blk >> 3;
    int d  = t2 % D_;
    int n  = t2 / D_;
    int h0 = hb << 3;

    int tid = threadIdx.x;
    int l   = tid & 63;
    int wid = tid >> 6;
    int nl  = l & 15;                     // spatial-in-tile (B n-dim, A m-dim)
    int kcg = l >> 4;                     // k-group (c/8)
    int kb  = kcg * 16;                   // byte offset of the 16B k-slice

    int bbase[2][4];
#pragma unroll
    for (int r = 0; r < 2; r++)
#pragma unroll
        for (int wq = 0; wq < 4; wq++)
            bbase[r][wq] = (((wid * 2 + r) * WP_) + wq * 16 + nl) * 64 + kb;
    int abase = nl * 64 + kb;             // + tl*2048 per tap; +1024 for A1

    f32x4 acc[2][4][2];
#pragma unroll
    for (int r = 0; r < 2; r++)
#pragma unroll
        for (int wq = 0; wq < 4; wq++)
#pragma unroll
            for (int hf = 0; hf < 2; hf++)
                acc[r][wq][hf] = (f32x4){0.f, 0.f, 0.f, 0.f};

    const unsigned short* xs0 = xt + ((size_t)(n * DP_ + d) * HP_ + h0) * ROW_;
    const unsigned short* ws0 = wn + (size_t)n * WPN_;
    int wun = tid & ~63;                  // wave-uniform lane-group base

#pragma unroll 1
    for (int od = 0; od < 3; od++) {
        const unsigned short* xs = xs0 + (size_t)od * ((size_t)HP_ * ROW_);
        const unsigned short* ws = ws0 + (size_t)od * 9 * (CO_ * C_);
#pragma unroll
        for (int base = 0; base < XCH_; base += 256) {
            int ch = base + tid;
            if (ch < XCH_)
                gl16(xs + (size_t)ch * 8, XB + (size_t)(base + wun) * 8);
        }
#pragma unroll
        for (int base = 0; base < WCH_; base += 256) {
            int ch = base + tid;
            if (ch < WCH_)
                gl16(ws + (size_t)ch * 8, WA + (size_t)(base + wun) * 8);
        }
        __syncthreads();                  // drains vmcnt before any ds_read

#pragma unroll
        for (int oh = 0; oh < 3; oh++) {
#pragma unroll
            for (int ow = 0; ow < 3; ow++) {
                int tl = oh * 3 + ow;
                const char* ab = (const char*)WA + tl * 2048 + abase;
                bf16x8 A0 = *(const bf16x8*)(ab);
                bf16x8 A1 = *(const bf16x8*)(ab + 1024);
#pragma unroll
                for (int r = 0; r < 2; r++)
#pragma unroll
                    for (int wq = 0; wq < 4; wq++) {
                        bf16x8 B = *(const bf16x8*)((const char*)XB
                                     + bbase[r][wq] + (oh * WP_ + ow) * 64);
                        acc[r][wq][0] = __builtin_amdgcn_mfma_f32_16x16x32_bf16(
                            A0, B, acc[r][wq][0], 0, 0, 0);
                        acc[r][wq][1] = __builtin_amdgcn_mfma_f32_16x16x32_bf16(
                            A1, B, acc[r][wq][1], 0, 0, 0);
                    }
            }
        }
        __syncthreads();                  // all reads done before next stage
    }

    int rquad = kcg << 2;
#pragma unroll
    for (int hf = 0; hf < 2; hf++)
#pragma unroll
        for (int j = 0; j < 4; j++) {
            int co = hf * 16 + rquad + j;
            float bv = bias[co];
#pragma unroll
            for (int r = 0; r < 2; r++) {
                int h = h0 + wid * 2 + r;
                float* op = out + ((size_t)(n * CO_ + co)) * DHW_
                                + (size_t)d * HW_ + (size_t)h * W_;
#pragma unroll
                for (int wq = 0; wq < 4; wq++)
                    op[wq * 16 + nl] = acc[r][wq][hf][j] + bv;
            }
        }
}

extern "C" void kernel_launch(void* const* d_in, const int* in_sizes, int n_in,
                              void* d_out, int out_size, void* d_ws, size_t ws_size,
                              hipStream_t stream) {
    const float* x      = (const float*)d_in[0];
    const float* weight = (const float*)d_in[1];
    const float* conv_w = (const float*)d_in[2];
    const float* conv_b = (const float*)d_in[3];
    const float* aw1    = (const float*)d_in[4];
    const float* ab1    = (const float*)d_in[5];
    const float* aw2    = (const float*)d_in[6];
    const float* ab2    = (const float*)d_in[7];
    const float* aw3    = (const float*)d_in[8];
    const float* ab3    = (const float*)d_in[9];
    float* out = (float*)d_out;

    unsigned short* xt  = (unsigned short*)d_ws;
    float* stats        = (float*)((char*)d_ws + XT_BYTES);
    float* attG         = (float*)((char*)d_ws + XT_BYTES + STATS_BYTES);
    float* part         = (float*)((char*)d_ws + XT_BYTES + STATS_BYTES + ATT_BYTES);
    unsigned short* wnb = (unsigned short*)((char*)d_ws + XT_BYTES + STATS_BYTES
                                            + ATT_BYTES + PART_BYTES);

    k_zero<<<dim3(N_ * 180), dim3(256), 0, stream>>>(xt);
    k_packstats<<<dim3(NPACK_), dim3(256), 0, stream>>>(x, xt, part);
    k_statreduce<<<dim3(N_ * C_), dim3(64), 0, stream>>>(part, stats);
    k_att<<<dim3(N_), dim3(128), 0, stream>>>(stats, aw1, ab1, aw2, ab2, aw3, ab3, attG);
    k_wcomb<<<dim3(N_ * CO_), dim3(256), 0, stream>>>(attG, weight, conv_w, wnb);
    k_conv<<<dim3(N_ * D_ * 8), dim3(256), 0, stream>>>(xt, wnb, conv_b, out);
}